// Round 9
// baseline (253.633 us; speedup 1.0000x reference)
//
#include <hip/hip_runtime.h>
#include <stdint.h>

#define D 64
#define K 512
#define NVEC 131072
#define MARGIN 0.03f

typedef short short8 __attribute__((ext_vector_type(8)));
typedef float f32x4 __attribute__((ext_vector_type(4)));

static __device__ __forceinline__ unsigned short f32_to_bf16_rne(float f) {
    union { float f; uint32_t u; } c; c.f = f;
    uint32_t u = c.u;
    uint32_t r = u + 0x7FFFu + ((u >> 16) & 1u);
    return (unsigned short)(r >> 16);
}
static __device__ __forceinline__ float bf16_to_f32(unsigned short h) {
    union { uint32_t u; float f; } c; c.u = ((uint32_t)h) << 16;
    return c.f;
}

// Kernel 1: w2half (exact round-2 chain), bf16 hi/lo codebook, zero counters.
__global__ __launch_bounds__(64) void vq_prep(const float* __restrict__ w,
                                              float* __restrict__ w2half,
                                              unsigned short* __restrict__ whi,
                                              unsigned short* __restrict__ wlo,
                                              unsigned int* __restrict__ flag_cnt,
                                              float* __restrict__ loss_slot) {
    int k = blockIdx.x * 64 + threadIdx.x;
    if (blockIdx.x == 0 && threadIdx.x == 0) { loss_slot[0] = 0.0f; flag_cnt[0] = 0u; }
    if (k < K) {
        const float* row = w + k * D;
        const float4* wv = (const float4*)row;
        float s0 = 0.f, s1 = 0.f, s2 = 0.f, s3 = 0.f;
#pragma unroll
        for (int i = 0; i < D / 4; ++i) {
            float4 t = wv[i];
            s0 = fmaf(t.x, t.x, s0);
            s1 = fmaf(t.y, t.y, s1);
            s2 = fmaf(t.z, t.z, s2);
            s3 = fmaf(t.w, t.w, s3);
        }
        w2half[k] = 0.5f * ((s0 + s1) + (s2 + s3));
#pragma unroll 8
        for (int d = 0; d < D; ++d) {
            float x = row[d];
            unsigned short h = f32_to_bf16_rne(x);
            whi[k * D + d] = h;
            wlo[k * D + d] = f32_to_bf16_rne(x - bf16_to_f32(h));
        }
    }
}

// Kernel 2: MFMA screening. Block = 4 waves x 16 vectors = 64 vectors, all 512
// codes. Per 16x16 tile: acc init 0.5|w|^2, 6 MFMA accumulate -(zh+zl).(wh+wl)
// (minus zl.wl). Per-lane (b1,i1,b2) tracking, 16-lane-group reduce, flag if
// gap <= MARGIN (rigorous eps bound ~0.011 < MARGIN).
// Fragment layouts (gfx950 16x16x32): A[m][k]: m=l&15, k=(l>>4)*8+j;
// B[k][n]: n=l&15, k=(l>>4)*8+j; D[row][col]: col=l&15, row=(l>>4)*4+r (m89).
__global__ __launch_bounds__(256) void vq_screen(const float* __restrict__ z_all,
                                                 const unsigned short* __restrict__ whi,
                                                 const unsigned short* __restrict__ wlo,
                                                 const float* __restrict__ w2half,
                                                 int* __restrict__ bidx_out,
                                                 unsigned int* __restrict__ flag_cnt,
                                                 unsigned int* __restrict__ flag_list) {
    __shared__ float w2s[K];
    const int t = threadIdx.x;
    for (int i = t; i < K; i += 256) w2s[i] = w2half[i];

    const int lane = t & 63;
    const int wid = t >> 6;
    const int v0 = blockIdx.x * 64 + wid * 16;
    const int row = lane & 15;   // A-row (vector) / B-col (code) selector
    const int g = lane >> 4;     // k-block 0..3

    // A fragments: lane reads z[v0+row][g*8+j] (+32 for second K-half),
    // negated then split hi/lo (negate-then-split is exact).
    const float* zbase = z_all + (size_t)(v0 + row) * D + g * 8;
    short8 ahi0, alo0, ahi1, alo1;
#pragma unroll
    for (int j = 0; j < 8; ++j) {
        float x0 = -zbase[j];
        unsigned short h0 = f32_to_bf16_rne(x0);
        ahi0[j] = (short)h0;
        alo0[j] = (short)f32_to_bf16_rne(x0 - bf16_to_f32(h0));
        float x1 = -zbase[32 + j];
        unsigned short h1 = f32_to_bf16_rne(x1);
        ahi1[j] = (short)h1;
        alo1[j] = (short)f32_to_bf16_rne(x1 - bf16_to_f32(h1));
    }
    __syncthreads();   // w2s ready

    float b1[4] = {3.4e38f, 3.4e38f, 3.4e38f, 3.4e38f};
    float b2[4] = {3.4e38f, 3.4e38f, 3.4e38f, 3.4e38f};
    int   i1[4] = {0, 0, 0, 0};

    for (int c0 = 0; c0 < K; c0 += 16) {
        const unsigned short* ph = whi + (size_t)(c0 + row) * D + g * 8;
        const unsigned short* pl = wlo + (size_t)(c0 + row) * D + g * 8;
        short8 bhi0 = *(const short8*)ph;
        short8 bhi1 = *(const short8*)(ph + 32);
        short8 blo0 = *(const short8*)pl;
        short8 blo1 = *(const short8*)(pl + 32);
        float wv = w2s[c0 + row];
        f32x4 acc = {wv, wv, wv, wv};
        acc = __builtin_amdgcn_mfma_f32_16x16x32_bf16(ahi0, bhi0, acc, 0, 0, 0);
        acc = __builtin_amdgcn_mfma_f32_16x16x32_bf16(ahi1, bhi1, acc, 0, 0, 0);
        acc = __builtin_amdgcn_mfma_f32_16x16x32_bf16(alo0, bhi0, acc, 0, 0, 0);
        acc = __builtin_amdgcn_mfma_f32_16x16x32_bf16(alo1, bhi1, acc, 0, 0, 0);
        acc = __builtin_amdgcn_mfma_f32_16x16x32_bf16(ahi0, blo0, acc, 0, 0, 0);
        acc = __builtin_amdgcn_mfma_f32_16x16x32_bf16(ahi1, blo1, acc, 0, 0, 0);
        const int kidx = c0 + row;
#pragma unroll
        for (int r = 0; r < 4; ++r) {
            float val = acc[r];
            if (val < b1[r]) { b2[r] = b1[r]; b1[r] = val; i1[r] = kidx; }
            else b2[r] = fminf(b2[r], val);
        }
    }

    // Reduce (b1,i1,b2) across the 16 lanes of each group (distinct cols).
#pragma unroll
    for (int m = 1; m < 16; m <<= 1) {
#pragma unroll
        for (int r = 0; r < 4; ++r) {
            float ob1 = __shfl_xor(b1[r], m, 16);
            float ob2 = __shfl_xor(b2[r], m, 16);
            int   oi1 = __shfl_xor(i1[r], m, 16);
            bool take = (ob1 < b1[r]) || (ob1 == b1[r] && oi1 < i1[r]);
            float loser = take ? b1[r] : ob1;
            b1[r] = take ? ob1 : b1[r];
            i1[r] = take ? oi1 : i1[r];
            b2[r] = fminf(fminf(b2[r], ob2), loser);
        }
    }

    if ((lane & 15) == 0) {
#pragma unroll
        for (int r = 0; r < 4; ++r) {
            int v = v0 + g * 4 + r;
            bidx_out[v] = i1[r];
            if (b2[r] - b1[r] <= MARGIN) {
                unsigned int pos = atomicAdd(flag_cnt, 1u);
                flag_list[pos] = (unsigned int)v;
            }
        }
    }
}

// Kernel 3: exact fp32 rescan for flagged vectors. One wave per vector; z row
// is wave-uniform -> s_load (round-2 chain arithmetic, identical per-chain
// sums). Lane j scans k = j, 64+j, ... (ascending); merge with first-index rule.
__global__ __launch_bounds__(256) void vq_rescan(const float* __restrict__ z_all,
                                                 const float* __restrict__ w,
                                                 const float* __restrict__ w2half,
                                                 const unsigned int* __restrict__ flag_cnt,
                                                 const unsigned int* __restrict__ flag_list,
                                                 int* __restrict__ bidx_out) {
    const int lane = threadIdx.x & 63;
    const int wid = __builtin_amdgcn_readfirstlane(threadIdx.x >> 6);
    const int gwave = blockIdx.x * 4 + wid;
    const int nw = gridDim.x * 4;
    const unsigned int n = flag_cnt[0];
    for (unsigned int it = gwave; it < n; it += nw) {
        const int v = (int)flag_list[it];                 // wave-uniform
        const float* __restrict__ zrow = z_all + (size_t)v * D;  // -> s_load
        float best = 3.402823466e+38f;
        int bidx = 0;
        for (int c = 0; c < 8; ++c) {
            const int k = c * 64 + lane;
            const float* __restrict__ wk = w + k * D;     // per-lane row
            float a0 = w2half[k], a1 = 0.f, a2 = 0.f, a3 = 0.f;
#pragma unroll
            for (int dd = 0; dd < D; dd += 4) {
                a0 = fmaf(-zrow[dd + 0], wk[dd + 0], a0);
                a1 = fmaf(-zrow[dd + 1], wk[dd + 1], a1);
                a2 = fmaf(-zrow[dd + 2], wk[dd + 2], a2);
                a3 = fmaf(-zrow[dd + 3], wk[dd + 3], a3);
            }
            float s = (a0 + a1) + (a2 + a3);
            if (s < best) { best = s; bidx = k; }         // ascending k per lane
        }
#pragma unroll
        for (int m = 1; m < 64; m <<= 1) {
            float ob = __shfl_xor(best, m, 64);
            int oi = __shfl_xor(bidx, m, 64);
            bool take = (ob < best) || (ob == best && oi < bidx);
            best = take ? ob : best;
            bidx = take ? oi : bidx;
        }
        if (lane == 0) bidx_out[v] = bidx;
    }
}

// Kernel 4: output + loss — byte-identical arithmetic to the round-2 epilogue.
__global__ __launch_bounds__(256) void vq_output(const float* __restrict__ z_all,
                                                 const float* __restrict__ w,
                                                 const int* __restrict__ bidx_arr,
                                                 float* __restrict__ out,
                                                 float* __restrict__ loss_slot) {
    const int v = blockIdx.x * 256 + threadIdx.x;
    const float4* zv = (const float4*)(z_all + (size_t)v * D);
    float zn[D];
#pragma unroll
    for (int i = 0; i < D / 4; ++i) {
        float4 tt = zv[i];
        zn[4 * i + 0] = -tt.x;
        zn[4 * i + 1] = -tt.y;
        zn[4 * i + 2] = -tt.z;
        zn[4 * i + 3] = -tt.w;
    }
    const int bidx = bidx_arr[v];
    const float4* qv = (const float4*)(w + (size_t)bidx * D);
    float4* ov = (float4*)(out + (size_t)v * D);
    float lsum = 0.f;
#pragma unroll
    for (int i = 0; i < D / 4; ++i) {
        float4 q = qv[i];
        float z0 = -zn[4 * i + 0], z1 = -zn[4 * i + 1];
        float z2 = -zn[4 * i + 2], z3 = -zn[4 * i + 3];
        float t0 = q.x - z0, t1 = q.y - z1, t2 = q.z - z2, t3 = q.w - z3;
        float4 o;
        o.x = z0 + t0;
        o.y = z1 + t1;
        o.z = z2 + t2;
        o.w = z3 + t3;
        ov[i] = o;
        lsum = fmaf(t0, t0, lsum);
        lsum = fmaf(t1, t1, lsum);
        lsum = fmaf(t2, t2, lsum);
        lsum = fmaf(t3, t3, lsum);
    }
#pragma unroll
    for (int off = 32; off > 0; off >>= 1) lsum += __shfl_down(lsum, off, 64);
    __shared__ float red[4];
    const int lane = threadIdx.x & 63;
    const int wid = threadIdx.x >> 6;
    if (lane == 0) red[wid] = lsum;
    __syncthreads();
    if (threadIdx.x == 0) {
        float s = 0.f;
#pragma unroll
        for (int i = 0; i < 4; ++i) s += red[i];
        atomicAdd(loss_slot, s * (1.25f / 8388608.0f));  // exact scale
    }
}

extern "C" void kernel_launch(void* const* d_in, const int* in_sizes, int n_in,
                              void* d_out, int out_size, void* d_ws, size_t ws_size,
                              hipStream_t stream) {
    const float* latents = (const float*)d_in[0];   // [8192,1024] f32
    const float* weight  = (const float*)d_in[1];   // [512,64] f32
    float* out = (float*)d_out;
    float* loss_slot = out + (size_t)NVEC * D;

    char* ws = (char*)d_ws;
    unsigned int* flag_cnt = (unsigned int*)ws;                    // 4 B
    int* bidx             = (int*)(ws + 256);                      // 512 KB
    unsigned int* flag_list = (unsigned int*)(ws + 256 + 524288);  // 512 KB
    float* w2half         = (float*)(ws + 256 + 1048576);          // 2 KB
    unsigned short* whi   = (unsigned short*)(ws + 256 + 1048576 + 2048);   // 64 KB
    unsigned short* wlo   = (unsigned short*)(ws + 256 + 1048576 + 2048 + 65536);

    vq_prep<<<8, 64, 0, stream>>>(weight, w2half, whi, wlo, flag_cnt, loss_slot);
    vq_screen<<<NVEC / 64, 256, 0, stream>>>(latents, whi, wlo, w2half,
                                             bidx, flag_cnt, flag_list);
    vq_rescan<<<512, 256, 0, stream>>>(latents, weight, w2half,
                                       flag_cnt, flag_list, bidx);
    vq_output<<<NVEC / 256, 256, 0, stream>>>(latents, weight, bidx, out, loss_slot);
}